// Round 7
// baseline (618.593 us; speedup 1.0000x reference)
//
#include <hip/hip_runtime.h>

#define H 128
#define EPS 1e-5f
#define NPB 256      // nodes per bucket (pow2); bucket = node >> 8

typedef __attribute__((ext_vector_type(8))) short bf16x8;
typedef __attribute__((ext_vector_type(4))) float f32x4;

__device__ inline unsigned short f2bf(float f){
  unsigned int u=__float_as_uint(f);
  return (unsigned short)((u + 0x7FFFu + ((u>>16)&1u))>>16);
}
__device__ inline unsigned int pack_bf16(float a, float b){
  unsigned int ua=__float_as_uint(a), ub=__float_as_uint(b);
  ua = (ua + 0x7FFFu + ((ua>>16)&1u)) >> 16;
  ub = (ub + 0x7FFFu + ((ub>>16)&1u)) & 0xFFFF0000u;
  return ua | ub;
}
__device__ inline float bflo(unsigned int u){ return __uint_as_float(u<<16); }
__device__ inline float bfhi(unsigned int u){ return __uint_as_float(u&0xFFFF0000u); }

// ============ CSR build via 2-level bucket sort ============
// Bucket = dest>>8. Binning writes land in per-block contiguous runs; final placement
// scatters only inside a ~32KB bucket window (L1/L2-resident). deg/dnorm/rowptr derived
// per bucket in LDS. pairs value carries ew*dnorm[row] so the SpMM gather source is
// UNSCALED bf16 h (= the residual buffer; one buffer serves both).

// ---- bucket histogram (block-local LDS, then 1 atomic per bucket) ----
__global__ __launch_bounds__(256) void k_bcount(const int* __restrict__ col, int E,
                                                int* __restrict__ bcnt){
  __shared__ int h[512];
  int t=threadIdx.x;
  for(int i=t;i<512;i+=256) h[i]=0;
  __syncthreads();
  int e0=blockIdx.x*4096, e1=min(e0+4096,E);
  for(int e=e0+t;e<e1;e+=256) atomicAdd(&h[((unsigned)col[e])>>8],1);
  __syncthreads();
  for(int i=t;i<512;i+=256) if(h[i]) atomicAdd(&bcnt[i],h[i]);
}

// ---- exclusive scan of bucket counts (single block) ----
__global__ void k_bscan(const int* __restrict__ bcnt, int B, int E,
                        int* __restrict__ bbase, int* __restrict__ cursor){
  __shared__ int s[512];
  int t=threadIdx.x;
  int v=(t<B)?bcnt[t]:0;
  s[t]=v; __syncthreads();
  for(int off=1;off<512;off<<=1){ int u=(t>=off)?s[t-off]:0; __syncthreads(); s[t]+=u; __syncthreads(); }
  if(t<B){ bbase[t]=s[t]-v; cursor[t]=s[t]-v; }
  if(t==0) bbase[B]=E;
}

// ---- binning: stg[...] = (local<<24 | row, ew), grouped by bucket ----
__global__ __launch_bounds__(256) void k_bfill(const int* __restrict__ row, const int* __restrict__ col,
    const float* __restrict__ ew, int E, int* __restrict__ cursor, uint2* __restrict__ stg){
  __shared__ int h[512];
  __shared__ int ofs[512];
  int t=threadIdx.x;
  for(int i=t;i<512;i+=256) h[i]=0;
  __syncthreads();
  int e0=blockIdx.x*4096, e1=min(e0+4096,E);
  for(int e=e0+t;e<e1;e+=256) atomicAdd(&h[((unsigned)col[e])>>8],1);
  __syncthreads();
  for(int i=t;i<512;i+=256) ofs[i] = h[i] ? atomicAdd(&cursor[i],h[i]) : 0;
  __syncthreads();
  for(int i=t;i<512;i+=256) h[i]=0;
  __syncthreads();
  for(int e=e0+t;e<e1;e+=256){
    unsigned d=(unsigned)col[e];
    int b=d>>8;
    int lp=atomicAdd(&h[b],1);
    stg[ofs[b]+lp]=make_uint2(((d&255u)<<24)|(unsigned)row[e], __float_as_uint(ew[e]));
  }
}

// ---- per-bucket: degree -> dnorm + rowptr (LDS count + scan) ----
__global__ __launch_bounds__(256) void k_p2a(const uint2* __restrict__ stg, const int* __restrict__ bbase,
    int N, int E, float* __restrict__ dnorm, int* __restrict__ rowptr){
  __shared__ int cnt[256];
  __shared__ int pre[256];
  int b=blockIdx.x, t=threadIdx.x;
  cnt[t]=0; __syncthreads();
  int s0=bbase[b], s1=bbase[b+1];
  for(int p=s0+t;p<s1;p+=256) atomicAdd(&cnt[stg[p].x>>24],1);
  __syncthreads();
  int v=cnt[t];
  pre[t]=v; __syncthreads();
  for(int off=1;off<256;off<<=1){ int u=(t>=off)?pre[t-off]:0; __syncthreads(); pre[t]+=u; __syncthreads(); }
  int node=(b<<8)+t;
  if(node<N){
    dnorm[node]= v>0 ? rsqrtf((float)v) : 0.f;   // nan_to_num: deg==0 -> coefficient 0
    rowptr[node]=s0+pre[t]-v;
    if(node==N-1) rowptr[N]=E;
  }
}

// ---- per-bucket: place records -> pairs, folding dnorm[row] into the value ----
__global__ __launch_bounds__(256) void k_p2b(const uint2* __restrict__ stg, const int* __restrict__ bbase,
    int N, const int* __restrict__ rowptr, const float* __restrict__ dnorm,
    float2* __restrict__ pairs){
  __shared__ int cur[256];
  int b=blockIdx.x, t=threadIdx.x;
  int node=(b<<8)+t;
  cur[t]=(node<N)?rowptr[node]:0;
  __syncthreads();
  int s0=bbase[b], s1=bbase[b+1];
  for(int p=s0+t;p<s1;p+=256){
    uint2 rec=stg[p];
    int r=(int)(rec.x&0xFFFFFFu);
    int pos=atomicAdd(&cur[rec.x>>24],1);
    pairs[pos]=make_float2(__int_as_float(r), __uint_as_float(rec.y)*dnorm[r]);
  }
}

// ---------------- SpMM bf16 (v7: half-wave / 4ch-per-lane) ----------------
// Wave per destination. Lane owns 4 channels (8B dwordx2); 32 lanes cover the 256B
// row; the two wave halves process even/odd edges -> per 16-edge batch: 8 uniform
// 16B pair loads + 8 independent 8B gathers (half the memory instructions of v6 for
// the same bytes in flight). __shfl_xor(32) combines halves; lanes 0-31 store.
__global__ __launch_bounds__(256) void k_spmm_bf(const float2* __restrict__ pairs,
    const int* __restrict__ rowptr, const float* __restrict__ dnorm,
    const unsigned short* __restrict__ hb, unsigned short* __restrict__ zb, int N){
  int wid=(blockIdx.x*256+threadIdx.x)>>6;
  int lane=threadIdx.x&63;
  if(wid>=N) return;
  int half=lane>>5, cl=lane&31;
  int beg=rowptr[wid], end=rowptr[wid+1];
  float a0=0.f,a1=0.f,a2=0.f,a3=0.f;
  int p=beg;

  if((p&1) && p<end){                    // align p to even (single record, low half only)
    float2 pr=pairs[p];
    float wv = half ? 0.f : pr.y;
    uint2 g=*(const uint2*)(hb + (((size_t)__float_as_int(pr.x))<<7) + (cl<<2));
    a0=fmaf(wv,bflo(g.x),a0); a1=fmaf(wv,bfhi(g.x),a1);
    a2=fmaf(wv,bflo(g.y),a2); a3=fmaf(wv,bfhi(g.y),a3);
    p++;
  }
  for(; p+16<=end; p+=16){               // 16 edges: 8 float4 pair loads + 8 gathers
    float4 f[8];
    #pragma unroll
    for(int j=0;j<8;j++) f[j]=((const float4*)(pairs+p))[j];
    int r[8]; float wv[8];
    #pragma unroll
    for(int j=0;j<8;j++){ r[j]=__float_as_int(half? f[j].z : f[j].x); wv[j]=half? f[j].w : f[j].y; }
    uint2 g[8];
    #pragma unroll
    for(int j=0;j<8;j++) g[j]=*(const uint2*)(hb + (((size_t)r[j])<<7) + (cl<<2));
    #pragma unroll
    for(int j=0;j<8;j++){
      a0=fmaf(wv[j],bflo(g[j].x),a0); a1=fmaf(wv[j],bfhi(g[j].x),a1);
      a2=fmaf(wv[j],bflo(g[j].y),a2); a3=fmaf(wv[j],bfhi(g[j].y),a3);
    }
  }
  for(; p+2<=end; p+=2){                 // 2-edge steps
    float4 f=*(const float4*)(pairs+p);
    int r=__float_as_int(half? f.z : f.x);
    float wv=half? f.w : f.y;
    uint2 g=*(const uint2*)(hb + (((size_t)r)<<7) + (cl<<2));
    a0=fmaf(wv,bflo(g.x),a0); a1=fmaf(wv,bfhi(g.x),a1);
    a2=fmaf(wv,bflo(g.y),a2); a3=fmaf(wv,bfhi(g.y),a3);
  }
  if(p<end){                             // final odd record
    float2 pr=pairs[p];
    float wv = half ? 0.f : pr.y;
    uint2 g=*(const uint2*)(hb + (((size_t)__float_as_int(pr.x))<<7) + (cl<<2));
    a0=fmaf(wv,bflo(g.x),a0); a1=fmaf(wv,bfhi(g.x),a1);
    a2=fmaf(wv,bflo(g.y),a2); a3=fmaf(wv,bfhi(g.y),a3);
  }

  a0+=__shfl_xor(a0,32); a1+=__shfl_xor(a1,32);
  a2+=__shfl_xor(a2,32); a3+=__shfl_xor(a3,32);
  if(half==0){
    float dn=dnorm[wid];
    uint2 pk; pk.x=pack_bf16(a0*dn,a1*dn); pk.y=pack_bf16(a2*dn,a3*dn);
    *(uint2*)(zb + ((size_t)wid<<7) + (cl<<2)) = pk;
  }
}

// ---------------- MFMA GEMM (N x 128 @ 128 x 128) + fused BN sum/sumsq ----------------
// bf16 MFMA 16x16x32. Wave = 64 rows x 128 cols (4 row-tiles x 8 ntiles, K = 4x32).
// W staged once/block into LDS transposed bf16 (pitch 136). A-frags straight from
// global (16B/lane). In-place safe. Layouts: A m=lane&15,k=quad*8+j; C/D col=lane&15,
// row=quad*4+reg [m89/m120-verified].
template<bool F32A>
__global__ __launch_bounds__(256,2) void k_gemm_bn(const void* __restrict__ Ap,
    const float* __restrict__ W, const float* __restrict__ bias,
    unsigned short* __restrict__ Zb, float* __restrict__ stats, int N){
  __shared__ __align__(16) unsigned short sWT[128*136];   // 34816 B
  int t=threadIdx.x;

  for(int it=t; it<4096; it+=256){
    float4 v=((const float4*)W)[it];
    int lin=it*4; int k=lin>>7; int c0=lin&127;
    sWT[(c0+0)*136+k]=f2bf(v.x);
    sWT[(c0+1)*136+k]=f2bf(v.y);
    sWT[(c0+2)*136+k]=f2bf(v.z);
    sWT[(c0+3)*136+k]=f2bf(v.w);
  }
  __syncthreads();

  int w=t>>6, lane=t&63, n=lane&15, quad=lane>>4;
  int r0w = blockIdx.x*256 + w*64;

  f32x4 acc[8][4];
  #pragma unroll
  for(int nt=0;nt<8;nt++)
    #pragma unroll
    for(int rt=0;rt<4;rt++){ f32x4 z4={0.f,0.f,0.f,0.f}; acc[nt][rt]=z4; }

  #pragma unroll
  for(int ks=0; ks<4; ks++){
    int k0 = ks*32 + quad*8;
    bf16x8 a[4];
    #pragma unroll
    for(int rt=0;rt<4;rt++){
      int r = r0w + rt*16 + n;
      bf16x8 af={0,0,0,0,0,0,0,0};
      if(r<N){
        if(F32A){
          const float* Af=(const float*)Ap;
          float4 u0=*(const float4*)&Af[(size_t)r*128 + k0];
          float4 u1=*(const float4*)&Af[(size_t)r*128 + k0 + 4];
          af[0]=(short)f2bf(u0.x); af[1]=(short)f2bf(u0.y);
          af[2]=(short)f2bf(u0.z); af[3]=(short)f2bf(u0.w);
          af[4]=(short)f2bf(u1.x); af[5]=(short)f2bf(u1.y);
          af[6]=(short)f2bf(u1.z); af[7]=(short)f2bf(u1.w);
        }else{
          af = *(const bf16x8*)((const unsigned short*)Ap + (size_t)r*128 + k0);
        }
      }
      a[rt]=af;
    }
    #pragma unroll
    for(int nt=0;nt<8;nt++){
      bf16x8 b = *(const bf16x8*)&sWT[(nt*16+n)*136 + k0];
      #pragma unroll
      for(int rt=0;rt<4;rt++)
        acc[nt][rt]=__builtin_amdgcn_mfma_f32_16x16x32_bf16(a[rt], b, acc[nt][rt], 0,0,0);
    }
  }

  __syncthreads();                        // reuse sWT for stats partials
  float* sS=(float*)sWT;                  // [16][132]
  float* sQ=sS + 16*132;                  // [16][132]
  #pragma unroll
  for(int nt=0;nt<8;nt++){
    int c=nt*16+n;
    float bc=bias[c];
    float s=0.f,q=0.f;
    #pragma unroll
    for(int rt=0;rt<4;rt++){
      #pragma unroll
      for(int i=0;i<4;i++){
        int r=r0w + rt*16 + quad*4 + i;
        if(r<N){
          float z=acc[nt][rt][i]+bc;
          Zb[(size_t)r*128+c]=f2bf(z);
          s+=z; q+=z*z;
        }
      }
    }
    sS[(w*4+quad)*132+c]=s;
    sQ[(w*4+quad)*132+c]=q;
  }
  __syncthreads();
  if(t<128){
    float s=0.f,q=0.f;
    #pragma unroll
    for(int g=0;g<16;g++){ s+=sS[g*132+t]; q+=sQ[g*132+t]; }
    atomicAdd(&stats[t],s); atomicAdd(&stats[128+t],q);
  }
}

// ---------------- apply: BN finalize (in-block) + scale/shift + ReLU + residual ----------------
// v7: k_bnfin fused — every block recomputes the 128-ch scale/shift from stats in LDS
// (1.5KB L2-hit reads per block; kills 3 tiny dispatches).
template<bool OUTF32>
__global__ __launch_bounds__(256) void k_apply(const unsigned short* __restrict__ Zb,
    const float* __restrict__ stats, const float* __restrict__ gamma,
    const float* __restrict__ beta, float invN,
    const unsigned short* __restrict__ res,
    float* __restrict__ outf, unsigned short* __restrict__ outb, int n4){
  __shared__ float smi[256];
  int t=threadIdx.x;
  if(t<128){
    float mean=stats[t]*invN;
    float var=stats[128+t]*invN - mean*mean;
    float inv=rsqrtf(var+EPS);
    float sc=inv*gamma[t];
    smi[t]=sc; smi[128+t]=beta[t]-mean*sc;
  }
  __syncthreads();
  int i=blockIdx.x*256+t;
  if(i>=n4) return;
  int c=(i&31)*4;
  uint2 zu=((const uint2*)Zb)[i];
  float4 z;
  z.x=bflo(zu.x); z.y=bfhi(zu.x);
  z.z=bflo(zu.y); z.w=bfhi(zu.y);
  float4 sc=*(const float4*)&smi[c];
  float4 sh=*(const float4*)&smi[128+c];
  float4 o;
  o.x=fmaxf(fmaf(z.x,sc.x,sh.x),0.f);
  o.y=fmaxf(fmaf(z.y,sc.y,sh.y),0.f);
  o.z=fmaxf(fmaf(z.z,sc.z,sh.z),0.f);
  o.w=fmaxf(fmaf(z.w,sc.w,sh.w),0.f);
  if(res){
    uint2 ru=((const uint2*)res)[i];
    o.x+=bflo(ru.x); o.y+=bfhi(ru.x);
    o.z+=bflo(ru.y); o.w+=bfhi(ru.y);
  }
  if(OUTF32){
    ((float4*)outf)[i]=o;
  }else{
    uint2 pk; pk.x=pack_bf16(o.x,o.y); pk.y=pack_bf16(o.z,o.w);
    ((uint2*)outb)[i]=pk;
  }
}

extern "C" void kernel_launch(void* const* d_in, const int* in_sizes, int n_in,
                              void* d_out, int out_size, void* d_ws, size_t ws_size,
                              hipStream_t stream){
  const float* x      = (const float*)d_in[0];
  const int*   ei     = (const int*)  d_in[1];
  const float* ew     = (const float*)d_in[2];
  const float* fc_w   = (const float*)d_in[3];
  const float* fc_b   = (const float*)d_in[4];
  const float* conv_w = (const float*)d_in[5];
  const float* conv_b = (const float*)d_in[6];
  const float* gamma  = (const float*)d_in[7];
  const float* beta   = (const float*)d_in[8];
  float* out = (float*)d_out;

  int N = in_sizes[0]/H;
  int E = in_sizes[2];
  const int* row = ei;
  const int* col = ei + E;
  int B = (N+NPB-1)/NPB;                 // buckets

  // workspace layout (~78 MB); pairs kept 16B-aligned for float4 record loads
  size_t NH = (size_t)N*H;
  unsigned short* zb   = (unsigned short*)d_ws;  // N*H bf16: SpMM out / GEMM in+out
  unsigned short* hbuf = zb + NH;                // N*H bf16: h (gather source + residual)
  uint2*  stg    = (uint2*)(hbuf + NH);          // E bucket-grouped records
  float2* pairs  = (float2*)(stg + E);           // E final CSR records (val = ew*dnorm[row])
  float*  stats  = (float*)(pairs + E);          // 3*256   } contiguous for
  int*    bcnt   = (int*)(stats + 768);          // 512     } single memset
  int*    bbase  = bcnt + 512;                   // 513
  int*    cursor = bbase + 513;                  // 512
  float*  dnorm  = (float*)(cursor + 512);       // N
  int*    rowptr = (int*)(dnorm + N);            // N+1

  hipMemsetAsync(stats, 0, sizeof(float)*(768+512), stream);

  int gE4k = (E+4095)/4096;
  k_bcount<<<gE4k,256,0,stream>>>(col,E,bcnt);
  k_bscan<<<1,512,0,stream>>>(bcnt,B,E,bbase,cursor);
  k_bfill<<<gE4k,256,0,stream>>>(row,col,ew,E,cursor,stg);
  k_p2a<<<B,256,0,stream>>>(stg,bbase,N,E,dnorm,rowptr);
  k_p2b<<<B,256,0,stream>>>(stg,bbase,N,rowptr,dnorm,pairs);

  int GB=(N+255)/256;
  int gApply=((N*32)+255)/256;
  int gSpmm=(N+3)/4;
  float invN=1.f/(float)N;

  // stage 0: h = relu(bn(x @ fc_w + fc_b))   [h kept in bf16 hbuf only]
  k_gemm_bn<true><<<GB,256,0,stream>>>(x, fc_w, fc_b, zb, stats, N);
  k_apply<false><<<gApply,256,0,stream>>>(zb, stats, gamma, beta, invN,
                                          nullptr, nullptr, hbuf, N*32);

  // layer 0: h = relu(bn(agg(h) @ W0 + b0)) + h   -> bf16 hbuf
  k_spmm_bf<<<gSpmm,256,0,stream>>>(pairs,rowptr,dnorm,hbuf,zb,N);
  k_gemm_bn<false><<<GB,256,0,stream>>>(zb, conv_w, conv_b, zb, stats+256, N);
  k_apply<false><<<gApply,256,0,stream>>>(zb, stats+256, gamma+H, beta+H, invN,
                                          hbuf, nullptr, hbuf, N*32);

  // layer 1: out = relu(bn(agg(h) @ W1 + b1)) + h  -> fp32 d_out (final)
  k_spmm_bf<<<gSpmm,256,0,stream>>>(pairs,rowptr,dnorm,hbuf,zb,N);
  k_gemm_bn<false><<<GB,256,0,stream>>>(zb, conv_w + (size_t)H*H, conv_b + H, zb, stats+512, N);
  k_apply<true><<<gApply,256,0,stream>>>(zb, stats+512, gamma+2*H, beta+2*H, invN,
                                         hbuf, out, nullptr, N*32);
}

// Round 8
// 462.476 us; speedup vs baseline: 1.3376x; 1.3376x over previous
//
#include <hip/hip_runtime.h>

#define H 128
#define EPS 1e-5f
#define NPB 256      // nodes per bucket (pow2); bucket = node >> 8

typedef __attribute__((ext_vector_type(8))) short bf16x8;
typedef __attribute__((ext_vector_type(4))) float f32x4;

__device__ inline unsigned short f2bf(float f){
  unsigned int u=__float_as_uint(f);
  return (unsigned short)((u + 0x7FFFu + ((u>>16)&1u))>>16);
}
__device__ inline unsigned int pack_bf16(float a, float b){
  unsigned int ua=__float_as_uint(a), ub=__float_as_uint(b);
  ua = (ua + 0x7FFFu + ((ua>>16)&1u)) >> 16;
  ub = (ub + 0x7FFFu + ((ub>>16)&1u)) & 0xFFFF0000u;
  return ua | ub;
}
__device__ inline float bflo(unsigned int u){ return __uint_as_float(u<<16); }
__device__ inline float bfhi(unsigned int u){ return __uint_as_float(u&0xFFFF0000u); }

// ============ CSR build via 2-level bucket sort ============
// Bucket = dest>>8. Binning writes land in per-block contiguous runs; final placement
// scatters only inside a ~32KB bucket window (L1/L2-resident). deg/dnorm/rowptr derived
// per bucket in LDS. pairs value carries ew*dnorm[row] so the SpMM gather source is
// UNSCALED bf16 h (= the residual buffer; one buffer serves both).

// ---- bucket histogram (block-local LDS, then 1 atomic per bucket) ----
__global__ __launch_bounds__(256) void k_bcount(const int* __restrict__ col, int E,
                                                int* __restrict__ bcnt){
  __shared__ int h[512];
  int t=threadIdx.x;
  for(int i=t;i<512;i+=256) h[i]=0;
  __syncthreads();
  int e0=blockIdx.x*4096, e1=min(e0+4096,E);
  for(int e=e0+t;e<e1;e+=256) atomicAdd(&h[((unsigned)col[e])>>8],1);
  __syncthreads();
  for(int i=t;i<512;i+=256) if(h[i]) atomicAdd(&bcnt[i],h[i]);
}

// ---- exclusive scan of bucket counts (single block) ----
__global__ void k_bscan(const int* __restrict__ bcnt, int B, int E,
                        int* __restrict__ bbase, int* __restrict__ cursor){
  __shared__ int s[512];
  int t=threadIdx.x;
  int v=(t<B)?bcnt[t]:0;
  s[t]=v; __syncthreads();
  for(int off=1;off<512;off<<=1){ int u=(t>=off)?s[t-off]:0; __syncthreads(); s[t]+=u; __syncthreads(); }
  if(t<B){ bbase[t]=s[t]-v; cursor[t]=s[t]-v; }
  if(t==0) bbase[B]=E;
}

// ---- binning: stg[...] = (local<<24 | row, ew), grouped by bucket ----
__global__ __launch_bounds__(256) void k_bfill(const int* __restrict__ row, const int* __restrict__ col,
    const float* __restrict__ ew, int E, int* __restrict__ cursor, uint2* __restrict__ stg){
  __shared__ int h[512];
  __shared__ int ofs[512];
  int t=threadIdx.x;
  for(int i=t;i<512;i+=256) h[i]=0;
  __syncthreads();
  int e0=blockIdx.x*4096, e1=min(e0+4096,E);
  for(int e=e0+t;e<e1;e+=256) atomicAdd(&h[((unsigned)col[e])>>8],1);
  __syncthreads();
  for(int i=t;i<512;i+=256) ofs[i] = h[i] ? atomicAdd(&cursor[i],h[i]) : 0;
  __syncthreads();
  for(int i=t;i<512;i+=256) h[i]=0;
  __syncthreads();
  for(int e=e0+t;e<e1;e+=256){
    unsigned d=(unsigned)col[e];
    int b=d>>8;
    int lp=atomicAdd(&h[b],1);
    stg[ofs[b]+lp]=make_uint2(((d&255u)<<24)|(unsigned)row[e], __float_as_uint(ew[e]));
  }
}

// ---- per-bucket: degree -> dnorm + rowptr (LDS count + scan) ----
__global__ __launch_bounds__(256) void k_p2a(const uint2* __restrict__ stg, const int* __restrict__ bbase,
    int N, int E, float* __restrict__ dnorm, int* __restrict__ rowptr){
  __shared__ int cnt[256];
  __shared__ int pre[256];
  int b=blockIdx.x, t=threadIdx.x;
  cnt[t]=0; __syncthreads();
  int s0=bbase[b], s1=bbase[b+1];
  for(int p=s0+t;p<s1;p+=256) atomicAdd(&cnt[stg[p].x>>24],1);
  __syncthreads();
  int v=cnt[t];
  pre[t]=v; __syncthreads();
  for(int off=1;off<256;off<<=1){ int u=(t>=off)?pre[t-off]:0; __syncthreads(); pre[t]+=u; __syncthreads(); }
  int node=(b<<8)+t;
  if(node<N){
    dnorm[node]= v>0 ? rsqrtf((float)v) : 0.f;   // nan_to_num: deg==0 -> coefficient 0
    rowptr[node]=s0+pre[t]-v;
    if(node==N-1) rowptr[N]=E;
  }
}

// ---- per-bucket: place records -> pairs, folding dnorm[row] into the value ----
__global__ __launch_bounds__(256) void k_p2b(const uint2* __restrict__ stg, const int* __restrict__ bbase,
    int N, const int* __restrict__ rowptr, const float* __restrict__ dnorm,
    float2* __restrict__ pairs){
  __shared__ int cur[256];
  int b=blockIdx.x, t=threadIdx.x;
  int node=(b<<8)+t;
  cur[t]=(node<N)?rowptr[node]:0;
  __syncthreads();
  int s0=bbase[b], s1=bbase[b+1];
  for(int p=s0+t;p<s1;p+=256){
    uint2 rec=stg[p];
    int r=(int)(rec.x&0xFFFFFFu);
    int pos=atomicAdd(&cur[rec.x>>24],1);
    pairs[pos]=make_float2(__int_as_float(r), __uint_as_float(rec.y)*dnorm[r]);
  }
}

// ---------------- SpMM bf16: wave/dest, 2 cols/lane, 16 gathers in flight ----------------
// v8 = v6 body (proven 72us). v7's half-wave batch (64 live VGPRs of arrays) spilled
// to scratch every iteration: WRITE_SIZE 25->410MB (=E*256B), dur 72->141us. Keep
// per-iteration live state <= pr[16]+u[16]. beg/end forced wave-uniform via
// readfirstlane so pair loads take the scalar/broadcast path.
__global__ __launch_bounds__(256) void k_spmm_bf(const float2* __restrict__ pairs,
    const int* __restrict__ rowptr, const float* __restrict__ dnorm,
    const unsigned short* __restrict__ hb, unsigned short* __restrict__ zb, int N){
  int wid=(blockIdx.x*256+threadIdx.x)>>6;
  int lane=threadIdx.x&63;
  if(wid>=N) return;
  int beg=__builtin_amdgcn_readfirstlane(rowptr[wid]);
  int end=__builtin_amdgcn_readfirstlane(rowptr[wid+1]);
  float ax=0.f, ay=0.f;
  int p=beg;
  for(; p+16<=end; p+=16){
    float2 pr[16]; unsigned int u[16];
    #pragma unroll
    for(int j=0;j<16;j++) pr[j]=pairs[p+j];
    #pragma unroll
    for(int j=0;j<16;j++)
      u[j]=*(const unsigned int*)(hb + (((size_t)__float_as_int(pr[j].x))<<7) + (lane<<1));
    #pragma unroll
    for(int j=0;j<16;j++){
      ax=fmaf(pr[j].y,bflo(u[j]),ax);
      ay=fmaf(pr[j].y,bfhi(u[j]),ay);
    }
  }
  for(; p+4<=end; p+=4){
    float2 pr[4]; unsigned int u[4];
    #pragma unroll
    for(int j=0;j<4;j++) pr[j]=pairs[p+j];
    #pragma unroll
    for(int j=0;j<4;j++)
      u[j]=*(const unsigned int*)(hb + (((size_t)__float_as_int(pr[j].x))<<7) + (lane<<1));
    #pragma unroll
    for(int j=0;j<4;j++){
      ax=fmaf(pr[j].y,bflo(u[j]),ax);
      ay=fmaf(pr[j].y,bfhi(u[j]),ay);
    }
  }
  for(; p<end; ++p){
    float2 pr=pairs[p];
    unsigned int u=*(const unsigned int*)(hb + (((size_t)__float_as_int(pr.x))<<7) + (lane<<1));
    ax=fmaf(pr.y,bflo(u),ax); ay=fmaf(pr.y,bfhi(u),ay);
  }
  float dn=dnorm[wid];
  *(unsigned int*)(zb + ((size_t)wid<<7) + (lane<<1)) = pack_bf16(ax*dn, ay*dn);
}

// ---------------- MFMA GEMM (N x 128 @ 128 x 128) + fused BN sum/sumsq ----------------
// bf16 MFMA 16x16x32. Wave = 64 rows x 128 cols (4 row-tiles x 8 ntiles, K = 4x32).
// W staged once/block into LDS transposed bf16 (pitch 136). A-frags straight from
// global (16B/lane). In-place safe. Layouts: A m=lane&15,k=quad*8+j; C/D col=lane&15,
// row=quad*4+reg [m89/m120-verified].
template<bool F32A>
__global__ __launch_bounds__(256,2) void k_gemm_bn(const void* __restrict__ Ap,
    const float* __restrict__ W, const float* __restrict__ bias,
    unsigned short* __restrict__ Zb, float* __restrict__ stats, int N){
  __shared__ __align__(16) unsigned short sWT[128*136];   // 34816 B
  int t=threadIdx.x;

  for(int it=t; it<4096; it+=256){
    float4 v=((const float4*)W)[it];
    int lin=it*4; int k=lin>>7; int c0=lin&127;
    sWT[(c0+0)*136+k]=f2bf(v.x);
    sWT[(c0+1)*136+k]=f2bf(v.y);
    sWT[(c0+2)*136+k]=f2bf(v.z);
    sWT[(c0+3)*136+k]=f2bf(v.w);
  }
  __syncthreads();

  int w=t>>6, lane=t&63, n=lane&15, quad=lane>>4;
  int r0w = blockIdx.x*256 + w*64;

  f32x4 acc[8][4];
  #pragma unroll
  for(int nt=0;nt<8;nt++)
    #pragma unroll
    for(int rt=0;rt<4;rt++){ f32x4 z4={0.f,0.f,0.f,0.f}; acc[nt][rt]=z4; }

  #pragma unroll
  for(int ks=0; ks<4; ks++){
    int k0 = ks*32 + quad*8;
    bf16x8 a[4];
    #pragma unroll
    for(int rt=0;rt<4;rt++){
      int r = r0w + rt*16 + n;
      bf16x8 af={0,0,0,0,0,0,0,0};
      if(r<N){
        if(F32A){
          const float* Af=(const float*)Ap;
          float4 u0=*(const float4*)&Af[(size_t)r*128 + k0];
          float4 u1=*(const float4*)&Af[(size_t)r*128 + k0 + 4];
          af[0]=(short)f2bf(u0.x); af[1]=(short)f2bf(u0.y);
          af[2]=(short)f2bf(u0.z); af[3]=(short)f2bf(u0.w);
          af[4]=(short)f2bf(u1.x); af[5]=(short)f2bf(u1.y);
          af[6]=(short)f2bf(u1.z); af[7]=(short)f2bf(u1.w);
        }else{
          af = *(const bf16x8*)((const unsigned short*)Ap + (size_t)r*128 + k0);
        }
      }
      a[rt]=af;
    }
    #pragma unroll
    for(int nt=0;nt<8;nt++){
      bf16x8 b = *(const bf16x8*)&sWT[(nt*16+n)*136 + k0];
      #pragma unroll
      for(int rt=0;rt<4;rt++)
        acc[nt][rt]=__builtin_amdgcn_mfma_f32_16x16x32_bf16(a[rt], b, acc[nt][rt], 0,0,0);
    }
  }

  __syncthreads();                        // reuse sWT for stats partials
  float* sS=(float*)sWT;                  // [16][132]
  float* sQ=sS + 16*132;                  // [16][132]
  #pragma unroll
  for(int nt=0;nt<8;nt++){
    int c=nt*16+n;
    float bc=bias[c];
    float s=0.f,q=0.f;
    #pragma unroll
    for(int rt=0;rt<4;rt++){
      #pragma unroll
      for(int i=0;i<4;i++){
        int r=r0w + rt*16 + quad*4 + i;
        if(r<N){
          float z=acc[nt][rt][i]+bc;
          Zb[(size_t)r*128+c]=f2bf(z);
          s+=z; q+=z*z;
        }
      }
    }
    sS[(w*4+quad)*132+c]=s;
    sQ[(w*4+quad)*132+c]=q;
  }
  __syncthreads();
  if(t<128){
    float s=0.f,q=0.f;
    #pragma unroll
    for(int g=0;g<16;g++){ s+=sS[g*132+t]; q+=sQ[g*132+t]; }
    atomicAdd(&stats[t],s); atomicAdd(&stats[128+t],q);
  }
}

// ---------------- apply: BN finalize (in-block) + scale/shift + ReLU + residual ----------------
// k_bnfin fused: every block recomputes the 128-ch scale/shift from stats in LDS
// (1.5KB L2-hit reads per block; kills 3 tiny dispatches).
template<bool OUTF32>
__global__ __launch_bounds__(256) void k_apply(const unsigned short* __restrict__ Zb,
    const float* __restrict__ stats, const float* __restrict__ gamma,
    const float* __restrict__ beta, float invN,
    const unsigned short* __restrict__ res,
    float* __restrict__ outf, unsigned short* __restrict__ outb, int n4){
  __shared__ float smi[256];
  int t=threadIdx.x;
  if(t<128){
    float mean=stats[t]*invN;
    float var=stats[128+t]*invN - mean*mean;
    float inv=rsqrtf(var+EPS);
    float sc=inv*gamma[t];
    smi[t]=sc; smi[128+t]=beta[t]-mean*sc;
  }
  __syncthreads();
  int i=blockIdx.x*256+t;
  if(i>=n4) return;
  int c=(i&31)*4;
  uint2 zu=((const uint2*)Zb)[i];
  float4 z;
  z.x=bflo(zu.x); z.y=bfhi(zu.x);
  z.z=bflo(zu.y); z.w=bfhi(zu.y);
  float4 sc=*(const float4*)&smi[c];
  float4 sh=*(const float4*)&smi[128+c];
  float4 o;
  o.x=fmaxf(fmaf(z.x,sc.x,sh.x),0.f);
  o.y=fmaxf(fmaf(z.y,sc.y,sh.y),0.f);
  o.z=fmaxf(fmaf(z.z,sc.z,sh.z),0.f);
  o.w=fmaxf(fmaf(z.w,sc.w,sh.w),0.f);
  if(res){
    uint2 ru=((const uint2*)res)[i];
    o.x+=bflo(ru.x); o.y+=bfhi(ru.x);
    o.z+=bflo(ru.y); o.w+=bfhi(ru.y);
  }
  if(OUTF32){
    ((float4*)outf)[i]=o;
  }else{
    uint2 pk; pk.x=pack_bf16(o.x,o.y); pk.y=pack_bf16(o.z,o.w);
    ((uint2*)outb)[i]=pk;
  }
}

extern "C" void kernel_launch(void* const* d_in, const int* in_sizes, int n_in,
                              void* d_out, int out_size, void* d_ws, size_t ws_size,
                              hipStream_t stream){
  const float* x      = (const float*)d_in[0];
  const int*   ei     = (const int*)  d_in[1];
  const float* ew     = (const float*)d_in[2];
  const float* fc_w   = (const float*)d_in[3];
  const float* fc_b   = (const float*)d_in[4];
  const float* conv_w = (const float*)d_in[5];
  const float* conv_b = (const float*)d_in[6];
  const float* gamma  = (const float*)d_in[7];
  const float* beta   = (const float*)d_in[8];
  float* out = (float*)d_out;

  int N = in_sizes[0]/H;
  int E = in_sizes[2];
  const int* row = ei;
  const int* col = ei + E;
  int B = (N+NPB-1)/NPB;                 // buckets

  // workspace layout (~78 MB)
  size_t NH = (size_t)N*H;
  unsigned short* zb   = (unsigned short*)d_ws;  // N*H bf16: SpMM out / GEMM in+out
  unsigned short* hbuf = zb + NH;                // N*H bf16: h (gather source + residual)
  uint2*  stg    = (uint2*)(hbuf + NH);          // E bucket-grouped records
  float2* pairs  = (float2*)(stg + E);           // E final CSR records (val = ew*dnorm[row])
  float*  stats  = (float*)(pairs + E);          // 3*256   } contiguous for
  int*    bcnt   = (int*)(stats + 768);          // 512     } single memset
  int*    bbase  = bcnt + 512;                   // 513
  int*    cursor = bbase + 513;                  // 512
  float*  dnorm  = (float*)(cursor + 512);       // N
  int*    rowptr = (int*)(dnorm + N);            // N+1

  hipMemsetAsync(stats, 0, sizeof(float)*(768+512), stream);

  int gE4k = (E+4095)/4096;
  k_bcount<<<gE4k,256,0,stream>>>(col,E,bcnt);
  k_bscan<<<1,512,0,stream>>>(bcnt,B,E,bbase,cursor);
  k_bfill<<<gE4k,256,0,stream>>>(row,col,ew,E,cursor,stg);
  k_p2a<<<B,256,0,stream>>>(stg,bbase,N,E,dnorm,rowptr);
  k_p2b<<<B,256,0,stream>>>(stg,bbase,N,rowptr,dnorm,pairs);

  int GB=(N+255)/256;
  int gApply=((N*32)+255)/256;
  int gSpmm=(N+3)/4;
  float invN=1.f/(float)N;

  // stage 0: h = relu(bn(x @ fc_w + fc_b))   [h kept in bf16 hbuf only]
  k_gemm_bn<true><<<GB,256,0,stream>>>(x, fc_w, fc_b, zb, stats, N);
  k_apply<false><<<gApply,256,0,stream>>>(zb, stats, gamma, beta, invN,
                                          nullptr, nullptr, hbuf, N*32);

  // layer 0: h = relu(bn(agg(h) @ W0 + b0)) + h   -> bf16 hbuf
  k_spmm_bf<<<gSpmm,256,0,stream>>>(pairs,rowptr,dnorm,hbuf,zb,N);
  k_gemm_bn<false><<<GB,256,0,stream>>>(zb, conv_w, conv_b, zb, stats+256, N);
  k_apply<false><<<gApply,256,0,stream>>>(zb, stats+256, gamma+H, beta+H, invN,
                                          hbuf, nullptr, hbuf, N*32);

  // layer 1: out = relu(bn(agg(h) @ W1 + b1)) + h  -> fp32 d_out (final)
  k_spmm_bf<<<gSpmm,256,0,stream>>>(pairs,rowptr,dnorm,hbuf,zb,N);
  k_gemm_bn<false><<<GB,256,0,stream>>>(zb, conv_w + (size_t)H*H, conv_b + H, zb, stats+512, N);
  k_apply<true><<<gApply,256,0,stream>>>(zb, stats+512, gamma+2*H, beta+2*H, invN,
                                         hbuf, out, nullptr, N*32);
}

// Round 9
// 453.757 us; speedup vs baseline: 1.3633x; 1.0192x over previous
//
#include <hip/hip_runtime.h>

#define H 128
#define EPS 1e-5f
#define NPB 256      // nodes per bucket (pow2); bucket = node >> 8

typedef __attribute__((ext_vector_type(8))) short bf16x8;
typedef __attribute__((ext_vector_type(4))) float f32x4;

__device__ inline unsigned short f2bf(float f){
  unsigned int u=__float_as_uint(f);
  return (unsigned short)((u + 0x7FFFu + ((u>>16)&1u))>>16);
}
__device__ inline unsigned int pack_bf16(float a, float b){
  unsigned int ua=__float_as_uint(a), ub=__float_as_uint(b);
  ua = (ua + 0x7FFFu + ((ua>>16)&1u)) >> 16;
  ub = (ub + 0x7FFFu + ((ub>>16)&1u)) & 0xFFFF0000u;
  return ua | ub;
}
__device__ inline float bflo(unsigned int u){ return __uint_as_float(u<<16); }
__device__ inline float bfhi(unsigned int u){ return __uint_as_float(u&0xFFFF0000u); }

// ============ CSR build via 2-level bucket sort ============
// Bucket = dest>>8. Binning writes land in per-block contiguous runs; final placement
// scatters only inside a ~32KB bucket window (L1/L2-resident). deg/dnorm/rowptr derived
// per bucket in LDS. pairs value carries ew*dnorm[row].

// ---- bucket histogram (block-local LDS, then 1 atomic per bucket) ----
__global__ __launch_bounds__(256) void k_bcount(const int* __restrict__ col, int E,
                                                int* __restrict__ bcnt){
  __shared__ int h[512];
  int t=threadIdx.x;
  for(int i=t;i<512;i+=256) h[i]=0;
  __syncthreads();
  int e0=blockIdx.x*4096, e1=min(e0+4096,E);
  for(int e=e0+t;e<e1;e+=256) atomicAdd(&h[((unsigned)col[e])>>8],1);
  __syncthreads();
  for(int i=t;i<512;i+=256) if(h[i]) atomicAdd(&bcnt[i],h[i]);
}

// ---- exclusive scan of bucket counts (single block) ----
__global__ void k_bscan(const int* __restrict__ bcnt, int B, int E,
                        int* __restrict__ bbase, int* __restrict__ cursor){
  __shared__ int s[512];
  int t=threadIdx.x;
  int v=(t<B)?bcnt[t]:0;
  s[t]=v; __syncthreads();
  for(int off=1;off<512;off<<=1){ int u=(t>=off)?s[t-off]:0; __syncthreads(); s[t]+=u; __syncthreads(); }
  if(t<B){ bbase[t]=s[t]-v; cursor[t]=s[t]-v; }
  if(t==0) bbase[B]=E;
}

// ---- binning: stg[...] = (local<<24 | row, ew), grouped by bucket ----
__global__ __launch_bounds__(256) void k_bfill(const int* __restrict__ row, const int* __restrict__ col,
    const float* __restrict__ ew, int E, int* __restrict__ cursor, uint2* __restrict__ stg){
  __shared__ int h[512];
  __shared__ int ofs[512];
  int t=threadIdx.x;
  for(int i=t;i<512;i+=256) h[i]=0;
  __syncthreads();
  int e0=blockIdx.x*4096, e1=min(e0+4096,E);
  for(int e=e0+t;e<e1;e+=256) atomicAdd(&h[((unsigned)col[e])>>8],1);
  __syncthreads();
  for(int i=t;i<512;i+=256) ofs[i] = h[i] ? atomicAdd(&cursor[i],h[i]) : 0;
  __syncthreads();
  for(int i=t;i<512;i+=256) h[i]=0;
  __syncthreads();
  for(int e=e0+t;e<e1;e+=256){
    unsigned d=(unsigned)col[e];
    int b=d>>8;
    int lp=atomicAdd(&h[b],1);
    stg[ofs[b]+lp]=make_uint2(((d&255u)<<24)|(unsigned)row[e], __float_as_uint(ew[e]));
  }
}

// ---- per-bucket: degree -> dnorm + rowptr (LDS count + scan) ----
__global__ __launch_bounds__(256) void k_p2a(const uint2* __restrict__ stg, const int* __restrict__ bbase,
    int N, int E, float* __restrict__ dnorm, int* __restrict__ rowptr){
  __shared__ int cnt[256];
  __shared__ int pre[256];
  int b=blockIdx.x, t=threadIdx.x;
  cnt[t]=0; __syncthreads();
  int s0=bbase[b], s1=bbase[b+1];
  for(int p=s0+t;p<s1;p+=256) atomicAdd(&cnt[stg[p].x>>24],1);
  __syncthreads();
  int v=cnt[t];
  pre[t]=v; __syncthreads();
  for(int off=1;off<256;off<<=1){ int u=(t>=off)?pre[t-off]:0; __syncthreads(); pre[t]+=u; __syncthreads(); }
  int node=(b<<8)+t;
  if(node<N){
    dnorm[node]= v>0 ? rsqrtf((float)v) : 0.f;   // nan_to_num: deg==0 -> coefficient 0
    rowptr[node]=s0+pre[t]-v;
    if(node==N-1) rowptr[N]=E;
  }
}

// ---- per-bucket: place records -> pairs, folding dnorm[row] into the value ----
__global__ __launch_bounds__(256) void k_p2b(const uint2* __restrict__ stg, const int* __restrict__ bbase,
    int N, const int* __restrict__ rowptr, const float* __restrict__ dnorm,
    float2* __restrict__ pairs){
  __shared__ int cur[256];
  int b=blockIdx.x, t=threadIdx.x;
  int node=(b<<8)+t;
  cur[t]=(node<N)?rowptr[node]:0;
  __syncthreads();
  int s0=bbase[b], s1=bbase[b+1];
  for(int p=s0+t;p<s1;p+=256){
    uint2 rec=stg[p];
    int r=(int)(rec.x&0xFFFFFFu);
    int pos=atomicAdd(&cur[rec.x>>24],1);
    pairs[pos]=make_float2(__int_as_float(r), __uint_as_float(rec.y)*dnorm[r]);
  }
}

// ---------------- SpMM bf16: wave/dest, 2 cols/lane, 16 gathers in flight ----------------
// Body = proven v8 (58us). v9: template BN0 applies stage-0 BN+ReLU inline to each
// gathered value (gather source = raw z0), eliminating the stage-0 apply pass entirely.
// Per-lane sc/sh for its 2 channels precomputed from stats (1.5KB, L2-broadcast).
// v7 lesson: keep per-iteration live state <= pr[16]+u[16] (wider batches spilled:
// WRITE_SIZE 25->410MB).
template<bool BN0>
__global__ __launch_bounds__(256) void k_spmm_bf(const float2* __restrict__ pairs,
    const int* __restrict__ rowptr, const float* __restrict__ dnorm,
    const unsigned short* __restrict__ hb, unsigned short* __restrict__ zb, int N,
    const float* __restrict__ bnst, const float* __restrict__ gamma,
    const float* __restrict__ beta, float invN){
  int wid=(blockIdx.x*256+threadIdx.x)>>6;
  int lane=threadIdx.x&63;
  if(wid>=N) return;
  float sc0=0.f,sh0=0.f,sc1=0.f,sh1=0.f;
  if(BN0){
    int c0=lane<<1;
    float m0=bnst[c0]*invN,      m1=bnst[c0+1]*invN;
    float v0=bnst[128+c0]*invN-m0*m0, v1=bnst[129+c0]*invN-m1*m1;
    sc0=rsqrtf(v0+EPS)*gamma[c0];   sh0=beta[c0]-m0*sc0;
    sc1=rsqrtf(v1+EPS)*gamma[c0+1]; sh1=beta[c0+1]-m1*sc1;
  }
  int beg=__builtin_amdgcn_readfirstlane(rowptr[wid]);
  int end=__builtin_amdgcn_readfirstlane(rowptr[wid+1]);
  float ax=0.f, ay=0.f;
  int p=beg;
  for(; p+16<=end; p+=16){
    float2 pr[16]; unsigned int u[16];
    #pragma unroll
    for(int j=0;j<16;j++) pr[j]=pairs[p+j];
    #pragma unroll
    for(int j=0;j<16;j++)
      u[j]=*(const unsigned int*)(hb + (((size_t)__float_as_int(pr[j].x))<<7) + (lane<<1));
    #pragma unroll
    for(int j=0;j<16;j++){
      float f0=bflo(u[j]), f1=bfhi(u[j]);
      if(BN0){ f0=fmaxf(fmaf(f0,sc0,sh0),0.f); f1=fmaxf(fmaf(f1,sc1,sh1),0.f); }
      ax=fmaf(pr[j].y,f0,ax); ay=fmaf(pr[j].y,f1,ay);
    }
  }
  for(; p+4<=end; p+=4){
    float2 pr[4]; unsigned int u[4];
    #pragma unroll
    for(int j=0;j<4;j++) pr[j]=pairs[p+j];
    #pragma unroll
    for(int j=0;j<4;j++)
      u[j]=*(const unsigned int*)(hb + (((size_t)__float_as_int(pr[j].x))<<7) + (lane<<1));
    #pragma unroll
    for(int j=0;j<4;j++){
      float f0=bflo(u[j]), f1=bfhi(u[j]);
      if(BN0){ f0=fmaxf(fmaf(f0,sc0,sh0),0.f); f1=fmaxf(fmaf(f1,sc1,sh1),0.f); }
      ax=fmaf(pr[j].y,f0,ax); ay=fmaf(pr[j].y,f1,ay);
    }
  }
  for(; p<end; ++p){
    float2 pr=pairs[p];
    unsigned int u=*(const unsigned int*)(hb + (((size_t)__float_as_int(pr.x))<<7) + (lane<<1));
    float f0=bflo(u), f1=bfhi(u);
    if(BN0){ f0=fmaxf(fmaf(f0,sc0,sh0),0.f); f1=fmaxf(fmaf(f1,sc1,sh1),0.f); }
    ax=fmaf(pr.y,f0,ax); ay=fmaf(pr.y,f1,ay);
  }
  float dn=dnorm[wid];
  *(unsigned int*)(zb + ((size_t)wid<<7) + (lane<<1)) = pack_bf16(ax*dn, ay*dn);
}

// ---------------- MFMA GEMM (N x 128 @ 128 x 128) + fused BN sum/sumsq ----------------
// bf16 MFMA 16x16x32. Wave = 64 rows x 128 cols (4 row-tiles x 8 ntiles, K = 4x32).
// W staged once/block into LDS transposed bf16 (pitch 136). A-frags straight from
// global (16B/lane). In-place safe. Layouts: A m=lane&15,k=quad*8+j; C/D col=lane&15,
// row=quad*4+reg [m89/m120-verified].
template<bool F32A>
__global__ __launch_bounds__(256,2) void k_gemm_bn(const void* __restrict__ Ap,
    const float* __restrict__ W, const float* __restrict__ bias,
    unsigned short* __restrict__ Zb, float* __restrict__ stats, int N){
  __shared__ __align__(16) unsigned short sWT[128*136];   // 34816 B
  int t=threadIdx.x;

  for(int it=t; it<4096; it+=256){
    float4 v=((const float4*)W)[it];
    int lin=it*4; int k=lin>>7; int c0=lin&127;
    sWT[(c0+0)*136+k]=f2bf(v.x);
    sWT[(c0+1)*136+k]=f2bf(v.y);
    sWT[(c0+2)*136+k]=f2bf(v.z);
    sWT[(c0+3)*136+k]=f2bf(v.w);
  }
  __syncthreads();

  int w=t>>6, lane=t&63, n=lane&15, quad=lane>>4;
  int r0w = blockIdx.x*256 + w*64;

  f32x4 acc[8][4];
  #pragma unroll
  for(int nt=0;nt<8;nt++)
    #pragma unroll
    for(int rt=0;rt<4;rt++){ f32x4 z4={0.f,0.f,0.f,0.f}; acc[nt][rt]=z4; }

  #pragma unroll
  for(int ks=0; ks<4; ks++){
    int k0 = ks*32 + quad*8;
    bf16x8 a[4];
    #pragma unroll
    for(int rt=0;rt<4;rt++){
      int r = r0w + rt*16 + n;
      bf16x8 af={0,0,0,0,0,0,0,0};
      if(r<N){
        if(F32A){
          const float* Af=(const float*)Ap;
          float4 u0=*(const float4*)&Af[(size_t)r*128 + k0];
          float4 u1=*(const float4*)&Af[(size_t)r*128 + k0 + 4];
          af[0]=(short)f2bf(u0.x); af[1]=(short)f2bf(u0.y);
          af[2]=(short)f2bf(u0.z); af[3]=(short)f2bf(u0.w);
          af[4]=(short)f2bf(u1.x); af[5]=(short)f2bf(u1.y);
          af[6]=(short)f2bf(u1.z); af[7]=(short)f2bf(u1.w);
        }else{
          af = *(const bf16x8*)((const unsigned short*)Ap + (size_t)r*128 + k0);
        }
      }
      a[rt]=af;
    }
    #pragma unroll
    for(int nt=0;nt<8;nt++){
      bf16x8 b = *(const bf16x8*)&sWT[(nt*16+n)*136 + k0];
      #pragma unroll
      for(int rt=0;rt<4;rt++)
        acc[nt][rt]=__builtin_amdgcn_mfma_f32_16x16x32_bf16(a[rt], b, acc[nt][rt], 0,0,0);
    }
  }

  __syncthreads();                        // reuse sWT for stats partials
  float* sS=(float*)sWT;                  // [16][132]
  float* sQ=sS + 16*132;                  // [16][132]
  #pragma unroll
  for(int nt=0;nt<8;nt++){
    int c=nt*16+n;
    float bc=bias[c];
    float s=0.f,q=0.f;
    #pragma unroll
    for(int rt=0;rt<4;rt++){
      #pragma unroll
      for(int i=0;i<4;i++){
        int r=r0w + rt*16 + quad*4 + i;
        if(r<N){
          float z=acc[nt][rt][i]+bc;
          Zb[(size_t)r*128+c]=f2bf(z);
          s+=z; q+=z*z;
        }
      }
    }
    sS[(w*4+quad)*132+c]=s;
    sQ[(w*4+quad)*132+c]=q;
  }
  __syncthreads();
  if(t<128){
    float s=0.f,q=0.f;
    #pragma unroll
    for(int g=0;g<16;g++){ s+=sS[g*132+t]; q+=sQ[g*132+t]; }
    atomicAdd(&stats[t],s); atomicAdd(&stats[128+t],q);
  }
}

// ---------------- apply: BN finalize (in-block) + scale/shift + ReLU + residual ----------------
// BNRES: residual operand is raw z0 -> apply stage-0 BN+ReLU inline (h0 never
// materialized). smi[0:256)=this stage scale/shift, smi[256:512)=residual stage's.
template<bool OUTF32, bool BNRES>
__global__ __launch_bounds__(256) void k_apply(const unsigned short* __restrict__ Zb,
    const float* __restrict__ stats, const float* __restrict__ gamma,
    const float* __restrict__ beta, float invN,
    const unsigned short* __restrict__ res,
    const float* __restrict__ rstats, const float* __restrict__ rgamma,
    const float* __restrict__ rbeta,
    float* __restrict__ outf, unsigned short* __restrict__ outb, int n4){
  __shared__ float smi[512];
  int t=threadIdx.x;
  if(t<128){
    float mean=stats[t]*invN;
    float var=stats[128+t]*invN - mean*mean;
    float sc=rsqrtf(var+EPS)*gamma[t];
    smi[t]=sc; smi[128+t]=beta[t]-mean*sc;
    if(BNRES){
      float rm=rstats[t]*invN;
      float rv=rstats[128+t]*invN - rm*rm;
      float rs=rsqrtf(rv+EPS)*rgamma[t];
      smi[256+t]=rs; smi[384+t]=rbeta[t]-rm*rs;
    }
  }
  __syncthreads();
  int i=blockIdx.x*256+t;
  if(i>=n4) return;
  int c=(i&31)*4;
  uint2 zu=((const uint2*)Zb)[i];
  float4 z;
  z.x=bflo(zu.x); z.y=bfhi(zu.x);
  z.z=bflo(zu.y); z.w=bfhi(zu.y);
  float4 sc=*(const float4*)&smi[c];
  float4 sh=*(const float4*)&smi[128+c];
  float4 o;
  o.x=fmaxf(fmaf(z.x,sc.x,sh.x),0.f);
  o.y=fmaxf(fmaf(z.y,sc.y,sh.y),0.f);
  o.z=fmaxf(fmaf(z.z,sc.z,sh.z),0.f);
  o.w=fmaxf(fmaf(z.w,sc.w,sh.w),0.f);
  if(res){
    uint2 ru=((const uint2*)res)[i];
    float4 r;
    r.x=bflo(ru.x); r.y=bfhi(ru.x);
    r.z=bflo(ru.y); r.w=bfhi(ru.y);
    if(BNRES){
      float4 rs=*(const float4*)&smi[256+c];
      float4 rh=*(const float4*)&smi[384+c];
      r.x=fmaxf(fmaf(r.x,rs.x,rh.x),0.f);
      r.y=fmaxf(fmaf(r.y,rs.y,rh.y),0.f);
      r.z=fmaxf(fmaf(r.z,rs.z,rh.z),0.f);
      r.w=fmaxf(fmaf(r.w,rs.w,rh.w),0.f);
    }
    o.x+=r.x; o.y+=r.y; o.z+=r.z; o.w+=r.w;
  }
  if(OUTF32){
    ((float4*)outf)[i]=o;
  }else{
    uint2 pk; pk.x=pack_bf16(o.x,o.y); pk.y=pack_bf16(o.z,o.w);
    ((uint2*)outb)[i]=pk;
  }
}

extern "C" void kernel_launch(void* const* d_in, const int* in_sizes, int n_in,
                              void* d_out, int out_size, void* d_ws, size_t ws_size,
                              hipStream_t stream){
  const float* x      = (const float*)d_in[0];
  const int*   ei     = (const int*)  d_in[1];
  const float* ew     = (const float*)d_in[2];
  const float* fc_w   = (const float*)d_in[3];
  const float* fc_b   = (const float*)d_in[4];
  const float* conv_w = (const float*)d_in[5];
  const float* conv_b = (const float*)d_in[6];
  const float* gamma  = (const float*)d_in[7];
  const float* beta   = (const float*)d_in[8];
  float* out = (float*)d_out;

  int N = in_sizes[0]/H;
  int E = in_sizes[2];
  const int* row = ei;
  const int* col = ei + E;
  int B = (N+NPB-1)/NPB;                 // buckets

  // workspace layout (~78 MB)
  size_t NH = (size_t)N*H;
  unsigned short* zb   = (unsigned short*)d_ws;  // N*H bf16: z0, then h1
  unsigned short* hbuf = zb + NH;                // N*H bf16: agg / z1 / z2
  uint2*  stg    = (uint2*)(hbuf + NH);          // E bucket-grouped records
  float2* pairs  = (float2*)(stg + E);           // E final CSR records (val = ew*dnorm[row])
  float*  stats  = (float*)(pairs + E);          // 3*256   } contiguous for
  int*    bcnt   = (int*)(stats + 768);          // 512     } single memset
  int*    bbase  = bcnt + 512;                   // 513
  int*    cursor = bbase + 513;                  // 512
  float*  dnorm  = (float*)(cursor + 512);       // N
  int*    rowptr = (int*)(dnorm + N);            // N+1

  hipMemsetAsync(stats, 0, sizeof(float)*(768+512), stream);

  int gE4k = (E+4095)/4096;
  k_bcount<<<gE4k,256,0,stream>>>(col,E,bcnt);
  k_bscan<<<1,512,0,stream>>>(bcnt,B,E,bbase,cursor);
  k_bfill<<<gE4k,256,0,stream>>>(row,col,ew,E,cursor,stg);
  k_p2a<<<B,256,0,stream>>>(stg,bbase,N,E,dnorm,rowptr);
  k_p2b<<<B,256,0,stream>>>(stg,bbase,N,rowptr,dnorm,pairs);

  int GB=(N+255)/256;
  int gApply=((N*32)+255)/256;
  int gSpmm=(N+3)/4;
  float invN=1.f/(float)N;

  // stage 0: z0 = x @ fc_w + fc_b  -> zb (h0 = relu(bn0(z0)) is NEVER materialized)
  k_gemm_bn<true><<<GB,256,0,stream>>>(x, fc_w, fc_b, zb, stats, N);

  // layer 0: agg = A_hat @ relu(bn0(z0))  [BN0 inline in gather]  -> hbuf
  k_spmm_bf<true><<<gSpmm,256,0,stream>>>(pairs,rowptr,dnorm, zb, hbuf, N,
                                          stats, gamma, beta, invN);
  k_gemm_bn<false><<<GB,256,0,stream>>>(hbuf, conv_w, conv_b, hbuf, stats+256, N);
  // h1 = relu(bn1(z1)) + relu(bn0(z0))  -> zb (in-place over z0)
  k_apply<false,true><<<gApply,256,0,stream>>>(hbuf, stats+256, gamma+H, beta+H, invN,
                                               zb, stats, gamma, beta,
                                               nullptr, zb, N*32);

  // layer 1: out = relu(bn2(agg(h1) @ W1 + b1)) + h1 -> fp32 d_out
  k_spmm_bf<false><<<gSpmm,256,0,stream>>>(pairs,rowptr,dnorm, zb, hbuf, N,
                                           nullptr, nullptr, nullptr, 0.f);
  k_gemm_bn<false><<<GB,256,0,stream>>>(hbuf, conv_w + (size_t)H*H, conv_b + H, hbuf, stats+512, N);
  k_apply<true,false><<<gApply,256,0,stream>>>(hbuf, stats+512, gamma+2*H, beta+2*H, invN,
                                               zb, nullptr, nullptr, nullptr,
                                               out, nullptr, N*32);
}